// Round 8
// baseline (404.426 us; speedup 1.0000x reference)
//
#include <hip/hip_runtime.h>
#include <hip/hip_cooperative_groups.h>

typedef __bf16 bf16x8 __attribute__((ext_vector_type(8)));
typedef float floatx4 __attribute__((ext_vector_type(4)));

#define NCH 128  // number of time chunks
#define CLEN 16  // chunk length (NCH*CLEN = 2048)

__device__ __forceinline__ unsigned short f2bf(float f) {
  unsigned int u = __builtin_bit_cast(unsigned int, f);
  u += 0x7fff + ((u >> 16) & 1);
  return (unsigned short)(u >> 16);
}
__device__ __forceinline__ float bf2f(unsigned short u) {
  unsigned int v = (unsigned int)u << 16;
  return __builtin_bit_cast(float, v);
}
__device__ __forceinline__ float bf2f_lo(unsigned int u) {
  return __builtin_bit_cast(float, u << 16);
}
__device__ __forceinline__ float bf2f_hi(unsigned int u) {
  return __builtin_bit_cast(float, u & 0xffff0000u);
}

// async 16B global->LDS copy; LDS dest = wave-uniform base + lane*16
__device__ __forceinline__ void async_copy16(const void* g, void* l) {
  __builtin_amdgcn_global_load_lds(
      (const __attribute__((address_space(1))) unsigned int*)g,
      (__attribute__((address_space(3))) unsigned int*)l, 16, 0, 0);
}

// ---------------- prep: cast x -> bf16 AND transpose+cast both weights ----------------
// blocks [0,8192): x cast.  blocks [8192,12288): 32x32 transpose tiles.
__global__ __launch_bounds__(256) void prep_kernel(
    const float* __restrict__ x, unsigned short* __restrict__ x_bf,
    const float* __restrict__ Win, unsigned short* __restrict__ winT,
    const float* __restrict__ Wout, unsigned short* __restrict__ woutT) {
  __shared__ float tile[32][33];
  int bx = blockIdx.x;
  int tid = threadIdx.x;
  if (bx < 8192) {
    int i = bx * 256 + tid;
    float4 v = ((const float4*)x)[i];
    ushort4 o;
    o.x = f2bf(v.x); o.y = f2bf(v.y); o.z = f2bf(v.z); o.w = f2bf(v.w);
    ((ushort4*)x_bf)[i] = o;
  } else {
    int tb = bx - 8192;          // [0,4096): 128 n-tiles x 32 k-tiles
    int nt = tb & 127, kt = tb >> 7;
    const float* W;
    unsigned short* WT;
    int ncols, n0;
    if (nt < 96) { W = Win; WT = winT; ncols = 3072; n0 = nt * 32; }
    else { W = Wout; WT = woutT; ncols = 1024; n0 = (nt - 96) * 32; }
    int k0 = kt * 32;
    int tx = tid & 31, ty8 = tid >> 5;
#pragma unroll
    for (int r = 0; r < 4; r++) {
      int ty = ty8 + r * 8;
      tile[ty][tx] = W[(size_t)(k0 + ty) * ncols + n0 + tx];
    }
    __syncthreads();
#pragma unroll
    for (int r = 0; r < 4; r++) {
      int ty = ty8 + r * 8;
      WT[(size_t)(n0 + ty) * 1024 + k0 + tx] = f2bf(tile[tx][ty]);
    }
  }
}

// ---------------- GEMM (bf16 MFMA, K=1024 fixed) ----------------
// global_load_lds staging (width=16) with XOR chunk swizzle:
// chunk (row, q) lives at LDS As[row*32 + (q ^ ((row>>1)&3))*8]
// Epilogue: activation -> LDS tile (padded) -> coalesced 32B/lane stores.
// EPI==1: gemm1 -> bf16 silu(inp) / sigmoid(og) / om=1-lam (segment is
// block-uniform since n0 % 128 == 0 and segments are 1024 wide).
// EPI==0: gemm2 -> fp32 out + bias.
template <int EPI>
__global__ __launch_bounds__(256) void gemm_kernel(
    const unsigned short* __restrict__ A, const unsigned short* __restrict__ BT,
    const float* __restrict__ bias, const float* __restrict__ lb,
    float* __restrict__ outf,
    unsigned short* __restrict__ o_inp, unsigned short* __restrict__ o_og,
    unsigned short* __restrict__ o_om) {
  __shared__ alignas(16) char smem_raw[17408];  // staging 16KB | epi tile (<=16.9KB)
  unsigned short* As = (unsigned short*)smem_raw;
  unsigned short* Bs = As + 128 * 32;
  const int m0 = blockIdx.x * 128, n0 = blockIdx.y * 128;
  const int tid = threadIdx.x;
  const int lane = tid & 63, wave = tid >> 6;
  const int wm = (wave >> 1) * 64, wn = (wave & 1) * 64;
  const int mrow = lane & 15, q = lane >> 4;
  const int qsw = q ^ ((mrow >> 1) & 3);  // read-side swizzled chunk position
  floatx4 acc[4][4] = {};
  // staging: wave w covers rows [w*32, w*32+32); 2 instrs of 16 rows per matrix
  const int r0 = wave * 32;
  const int srow = r0 + (lane >> 2);
  const int qs = (lane & 3) ^ ((srow >> 1) & 3);  // global chunk this lane fetches
  const unsigned short* gA0 = A + (size_t)(m0 + srow) * 1024 + qs * 8;
  const unsigned short* gA1 = gA0 + (size_t)16 * 1024;
  const unsigned short* gB0 = BT + (size_t)(n0 + srow) * 1024 + qs * 8;
  const unsigned short* gB1 = gB0 + (size_t)16 * 1024;
  unsigned short* lA0 = &As[r0 * 32];
  unsigned short* lA1 = &As[(r0 + 16) * 32];
  unsigned short* lB0 = &Bs[r0 * 32];
  unsigned short* lB1 = &Bs[(r0 + 16) * 32];
  for (int kt = 0; kt < 1024; kt += 32) {
    __syncthreads();  // previous tile fully consumed
    async_copy16(gA0, lA0);
    async_copy16(gA1, lA1);
    async_copy16(gB0, lB0);
    async_copy16(gB1, lB1);
    gA0 += 32; gA1 += 32; gB0 += 32; gB1 += 32;
    __syncthreads();  // drains vmcnt -> staging complete
    bf16x8 af[4], bf[4];
#pragma unroll
    for (int i = 0; i < 4; i++) af[i] = *(const bf16x8*)&As[(wm + i * 16 + mrow) * 32 + qsw * 8];
#pragma unroll
    for (int j = 0; j < 4; j++) bf[j] = *(const bf16x8*)&Bs[(wn + j * 16 + mrow) * 32 + qsw * 8];
#pragma unroll
    for (int i = 0; i < 4; i++)
#pragma unroll
      for (int j = 0; j < 4; j++)
        acc[i][j] = __builtin_amdgcn_mfma_f32_16x16x32_bf16(af[i], bf[j], acc[i][j], 0, 0, 0);
  }
  // ---- epilogue ----
  const int er = tid >> 3;            // 0..31: local row for coalesced store
  const int ec = (tid & 7) * 16;      // 0..112: col chunk base
  const int rgbase = m0 + (er & 15) + (er >> 4) * 64;  // + i*16 later
  const int lr = (wm ? 16 : 0) + q * 4;                // local row base for C writes
  float bi[4];
  int cidx[4];
#pragma unroll
  for (int j = 0; j < 4; j++) {
    cidx[j] = n0 + wn + j * 16 + mrow;
    bi[j] = bias[cidx[j]];
  }
  if (EPI == 1) {
    unsigned short* Cs = (unsigned short*)smem_raw;  // 32 x 136 bf16
    const int seg = n0 >> 10;
    unsigned short* dst = (seg == 0) ? o_inp : (seg == 1) ? o_og : o_om;
    float Lv[4];
    if (seg == 2) {
#pragma unroll
      for (int j = 0; j < 4; j++) Lv[j] = lb[cidx[j] & 1023];
    }
#pragma unroll
    for (int i = 0; i < 4; i++) {
      __syncthreads();
#pragma unroll
      for (int j = 0; j < 4; j++) {
        const int lc = wn + j * 16 + mrow;
#pragma unroll
        for (int g = 0; g < 4; g++) {
          float v = acc[i][j][g] + bi[j];
          unsigned short ob;
          if (seg == 0) { float s = 1.f / (1.f + __expf(-v)); ob = f2bf(v * s); }
          else if (seg == 1) { float s = 1.f / (1.f + __expf(-v)); ob = f2bf(s); }
          else { float sm = 1.f / (1.f + __expf(v)); ob = f2bf((1.f - Lv[j]) * sm); }
          Cs[(lr + g) * 136 + lc] = ob;
        }
      }
      __syncthreads();
      uint4 v0 = *(uint4*)&Cs[er * 136 + ec];
      uint4 v1 = *(uint4*)&Cs[er * 136 + ec + 8];
      size_t ro = (size_t)(rgbase + i * 16) * 1024 + (n0 & 1023) + ec;
      *(uint4*)&dst[ro] = v0;
      *(uint4*)&dst[ro + 8] = v1;
    }
  } else {
    float* Cf = (float*)smem_raw;  // 32 x 132 fp32
#pragma unroll
    for (int i = 0; i < 4; i++) {
      __syncthreads();
#pragma unroll
      for (int j = 0; j < 4; j++) {
        const int lc = wn + j * 16 + mrow;
#pragma unroll
        for (int g = 0; g < 4; g++) Cf[(lr + g) * 132 + lc] = acc[i][j][g] + bi[j];
      }
      __syncthreads();
      size_t ro = (size_t)(rgbase + i * 16) * 1024 + n0 + ec;
#pragma unroll
      for (int k = 0; k < 4; k++) {
        float4 v = *(float4*)&Cf[er * 132 + ec + k * 4];
        *(float4*)&outf[ro + k * 4] = v;
      }
    }
  }
}

// ---------------- fused middle: chunk scan + inter-chunk scan + replay + LN ----------------
// cooperative launch: 256 blocks x 512 threads, 1 block/CU co-resident.
// Phase A: per-(c,b) chunk summaries (each block handles cb and cb+256).
// Phase B: 128-chunk serial scan, 64 threads x 256 blocks (spread over CUs).
//          NOTE: sumA holds prod(lam) directly — use it unmodified.
// Phase C: replay fwd+rev from register stash + LN + bf16 y (2 chunks/block).
// channel layout per (b,h): ch = dd*2+e;  a=lam[dd]=1-om[dd], u=om[dd]*inp[e]
__global__ __launch_bounds__(512, 2) void scan_mid_kernel(
    const unsigned short* __restrict__ om, const unsigned short* __restrict__ ip,
    const unsigned short* __restrict__ og,
    float* __restrict__ sumA, float* __restrict__ sumBf, float* __restrict__ sumBr,
    float* __restrict__ initF, float* __restrict__ initR,
    const float* __restrict__ gamma, const float* __restrict__ beta,
    unsigned short* __restrict__ ybf) {
  __shared__ float tile[8][1024];
  __shared__ float ldsG[1024];
  __shared__ float ldsB[1024];
  const int h = threadIdx.x;  // 0..511
  // gamma/beta preload (used in phase C; LDS untouched by phases A/B)
  *(float2*)&ldsG[2 * h] = *(const float2*)(gamma + 2 * h);
  *(float2*)&ldsB[2 * h] = *(const float2*)(beta + 2 * h);

  // ---- phase A ----
#pragma unroll
  for (int rep = 0; rep < 2; rep++) {
    const int cb = blockIdx.x + rep * 256;
    const int b = cb & 3, c = cb >> 2;
    const int idx = cb * 512 + h;
    long base = ((long)c * CLEN * 4 + b) * 1024 + 2 * h;
    float p0 = 1.f, p1 = 1.f;
    float s00 = 0.f, s01 = 0.f, s10 = 0.f, s11 = 0.f;
    float r00 = 0.f, r01 = 0.f, r10 = 0.f, r11 = 0.f;
#pragma unroll
    for (int t = 0; t < CLEN; t++) {
      unsigned int l2 = *(const unsigned int*)(om + base);
      unsigned int i2 = *(const unsigned int*)(ip + base);
      base += 4096;
      float omx = bf2f_lo(l2), omy = bf2f_hi(l2);
      float ipx = bf2f_lo(i2), ipy = bf2f_hi(i2);
      float lx = 1.f - omx, ly = 1.f - omy;
      float u00 = omx * ipx, u01 = omx * ipy, u10 = omy * ipx, u11 = omy * ipy;
      r00 += p0 * u00; r01 += p0 * u01; r10 += p1 * u10; r11 += p1 * u11;
      s00 = lx * s00 + u00; s01 = lx * s01 + u01;
      s10 = ly * s10 + u10; s11 = ly * s11 + u11;
      p0 *= lx; p1 *= ly;
    }
    ((float2*)sumA)[idx] = make_float2(p0, p1);
    ((float4*)sumBf)[idx] = make_float4(s00, s01, s10, s11);
    ((float4*)sumBr)[idx] = make_float4(r00, r01, r10, r11);
  }
  __threadfence();
  cooperative_groups::this_grid().sync();

  // ---- phase B ----
  if (h < 64) {
    int tid = blockIdx.x * 64 + h;  // 16384
    int dir = tid >> 13;
    int rem = tid & 8191;   // (b*512+h)*4 + ch
    int ch = rem & 3;
    int bh = rem >> 2;
    int dd = ch >> 1;
    if (dir == 0) {
      float H = 0.f;
#pragma unroll 4
      for (int c = 0; c < NCH; c++) {
        int si = c * 2048 + bh;
        initF[(size_t)si * 4 + ch] = H;
        H = sumA[(size_t)si * 2 + dd] * H + sumBf[(size_t)si * 4 + ch];
      }
    } else {
      float G = 0.f;
#pragma unroll 4
      for (int c = NCH - 1; c >= 0; c--) {
        int si = c * 2048 + bh;
        initR[(size_t)si * 4 + ch] = G;
        G = sumA[(size_t)si * 2 + dd] * G + sumBr[(size_t)si * 4 + ch];
      }
    }
  }
  __threadfence();
  cooperative_groups::this_grid().sync();

  // ---- phase C ----
  const int lane = h & 63, wv = h >> 6;
#pragma unroll 1
  for (int rep = 0; rep < 2; rep++) {
    const int cb = blockIdx.x + rep * 256;
    const int b = cb & 3, c = cb >> 2;
    const int idx = cb * 512 + h;
    float4 F = ((const float4*)initF)[idx];
    float4 R = ((const float4*)initR)[idx];
    float outx[CLEN], outy[CLEN];
    unsigned int lS[CLEN], iS[CLEN], oS[CLEN];
    const long base = ((long)c * CLEN * 4 + b) * 1024 + 2 * h;
    float h00 = F.x, h01 = F.y, h10 = F.z, h11 = F.w;
    long p = base;
#pragma unroll
    for (int t = 0; t < CLEN; t++) {
      unsigned int l2 = *(const unsigned int*)(om + p);
      unsigned int i2 = *(const unsigned int*)(ip + p);
      unsigned int o2 = *(const unsigned int*)(og + p);
      p += 4096;
      lS[t] = l2; iS[t] = i2; oS[t] = o2;
      float omx = bf2f_lo(l2), omy = bf2f_hi(l2);
      float ipx = bf2f_lo(i2), ipy = bf2f_hi(i2);
      float ox = bf2f_lo(o2), oy = bf2f_hi(o2);
      float lx = 1.f - omx, ly = 1.f - omy;
      h00 = lx * h00 + omx * ipx; h01 = lx * h01 + omx * ipy;
      h10 = ly * h10 + omy * ipx; h11 = ly * h11 + omy * ipy;
      outx[t] = h00 * ox + h10 * oy;
      outy[t] = h01 * ox + h11 * oy;
    }
    float g00 = R.x, g01 = R.y, g10 = R.z, g11 = R.w;
#pragma unroll
    for (int t = CLEN - 1; t >= 0; t--) {
      unsigned int l2 = lS[t], i2 = iS[t], o2 = oS[t];
      float omx = bf2f_lo(l2), omy = bf2f_hi(l2);
      float ipx = bf2f_lo(i2), ipy = bf2f_hi(i2);
      float ox = bf2f_lo(o2), oy = bf2f_hi(o2);
      float lx = 1.f - omx, ly = 1.f - omy;
      g00 = omx * ipx + lx * g00; g01 = omx * ipy + lx * g01;
      g10 = omy * ipx + ly * g10; g11 = omy * ipy + ly * g11;
      outx[t] += g00 * ox + g10 * oy;
      outy[t] += g01 * ox + g11 * oy;
    }
    // layernorm in groups of 8 t-rows via LDS transpose
#pragma unroll
    for (int g = 0; g < CLEN / 8; g++) {
      __syncthreads();  // prior group reads done (and gamma/beta preload on first)
#pragma unroll
      for (int r = 0; r < 8; r++) {
        float2 v2 = make_float2(outx[g * 8 + r], outy[g * 8 + r]);
        *(float2*)&tile[r][2 * h] = v2;
      }
      __syncthreads();
      // wave wv reduces + normalizes row wv of this group
      const int t = g * 8 + wv;
      float4 v[4];
#pragma unroll
      for (int k = 0; k < 4; k++) v[k] = *(const float4*)&tile[wv][lane * 16 + k * 4];
      float s = 0.f, s2 = 0.f;
#pragma unroll
      for (int k = 0; k < 4; k++) {
        s += v[k].x + v[k].y + v[k].z + v[k].w;
        s2 += v[k].x * v[k].x + v[k].y * v[k].y + v[k].z * v[k].z + v[k].w * v[k].w;
      }
#pragma unroll
      for (int off = 1; off < 64; off <<= 1) {
        s += __shfl_xor(s, off);
        s2 += __shfl_xor(s2, off);
      }
      float mean = s * (1.f / 1024.f);
      float var = s2 * (1.f / 1024.f) - mean * mean;
      float rstd = rsqrtf(var + 1e-5f);
      unsigned short o16[16];
#pragma unroll
      for (int k = 0; k < 4; k++) {
        float* vv = (float*)&v[k];
#pragma unroll
        for (int e = 0; e < 4; e++) {
          int ch = lane * 16 + k * 4 + e;
          o16[k * 4 + e] = f2bf((vv[e] - mean) * rstd * ldsG[ch] + ldsB[ch]);
        }
      }
      size_t rowo = ((size_t)(c * CLEN + t) * 4 + b) * 1024 + lane * 16;
      *(uint4*)(ybf + rowo) = *(uint4*)&o16[0];
      *(uint4*)(ybf + rowo + 8) = *(uint4*)&o16[8];
    }
    __syncthreads();  // tile reuse across reps
  }
}

// ---------------- launch ----------------
extern "C" void kernel_launch(void* const* d_in, const int* in_sizes, int n_in,
                              void* d_out, int out_size, void* d_ws, size_t ws_size,
                              hipStream_t stream) {
  const float* x = (const float*)d_in[0];
  const float* lb = (const float*)d_in[1];
  const float* Win = (const float*)d_in[2];
  const float* bin = (const float*)d_in[3];
  const float* Wout = (const float*)d_in[4];
  const float* bout = (const float*)d_in[5];
  const float* gamma = (const float*)d_in[6];
  const float* beta = (const float*)d_in[7];
  float* out = (float*)d_out;

  char* ws = (char*)d_ws;
  size_t off = 0;
  auto alloc = [&](size_t bytes) {
    void* p = ws + off;
    off += (bytes + 255) & ~(size_t)255;
    return p;
  };
  unsigned short* x_bf = (unsigned short*)alloc(8192ull * 1024 * 2);
  unsigned short* winT = (unsigned short*)alloc(3072ull * 1024 * 2);
  unsigned short* woutT = (unsigned short*)alloc(1024ull * 1024 * 2);
  unsigned short* inp_b = (unsigned short*)alloc(8192ull * 1024 * 2);
  unsigned short* og_b = (unsigned short*)alloc(8192ull * 1024 * 2);
  unsigned short* om_b = (unsigned short*)alloc(8192ull * 1024 * 2);
  unsigned short* y_bf = (unsigned short*)alloc(8192ull * 1024 * 2);
  float* sumA = (float*)alloc((size_t)NCH * 4 * 512 * 2 * 4);
  float* sumBf = (float*)alloc((size_t)NCH * 4 * 512 * 4 * 4);
  float* sumBr = (float*)alloc((size_t)NCH * 4 * 512 * 4 * 4);
  float* initF = (float*)alloc((size_t)NCH * 4 * 512 * 4 * 4);
  float* initR = (float*)alloc((size_t)NCH * 4 * 512 * 4 * 4);

  prep_kernel<<<12288, 256, 0, stream>>>(x, x_bf, Win, winT, Wout, woutT);
  gemm_kernel<1><<<dim3(64, 24), 256, 0, stream>>>(x_bf, winT, bin, lb, nullptr, inp_b, og_b, om_b);
  {
    const unsigned short* a_om = om_b;
    const unsigned short* a_ip = inp_b;
    const unsigned short* a_og = og_b;
    float* a_sumA = sumA; float* a_sumBf = sumBf; float* a_sumBr = sumBr;
    float* a_initF = initF; float* a_initR = initR;
    const float* a_gamma = gamma; const float* a_beta = beta;
    unsigned short* a_y = y_bf;
    void* args[] = {(void*)&a_om, (void*)&a_ip, (void*)&a_og,
                    (void*)&a_sumA, (void*)&a_sumBf, (void*)&a_sumBr,
                    (void*)&a_initF, (void*)&a_initR,
                    (void*)&a_gamma, (void*)&a_beta, (void*)&a_y};
    hipLaunchCooperativeKernel((const void*)scan_mid_kernel, dim3(256), dim3(512),
                               args, 0, stream);
  }
  gemm_kernel<0><<<dim3(64, 8), 256, 0, stream>>>(y_bf, woutT, bout, nullptr, out, nullptr, nullptr, nullptr);
}

// Round 9
// 245.623 us; speedup vs baseline: 1.6465x; 1.6465x over previous
//
#include <hip/hip_runtime.h>

typedef __bf16 bf16x8 __attribute__((ext_vector_type(8)));
typedef float floatx4 __attribute__((ext_vector_type(4)));

#define NCH 128  // number of time chunks
#define CLEN 16  // chunk length (NCH*CLEN = 2048)

__device__ __forceinline__ unsigned short f2bf(float f) {
  unsigned int u = __builtin_bit_cast(unsigned int, f);
  u += 0x7fff + ((u >> 16) & 1);
  return (unsigned short)(u >> 16);
}
__device__ __forceinline__ float bf2f(unsigned short u) {
  unsigned int v = (unsigned int)u << 16;
  return __builtin_bit_cast(float, v);
}
__device__ __forceinline__ float bf2f_lo(unsigned int u) {
  return __builtin_bit_cast(float, u << 16);
}
__device__ __forceinline__ float bf2f_hi(unsigned int u) {
  return __builtin_bit_cast(float, u & 0xffff0000u);
}

// async 16B global->LDS copy; LDS dest = wave-uniform base + lane*16
__device__ __forceinline__ void async_copy16(const void* g, void* l) {
  __builtin_amdgcn_global_load_lds(
      (const __attribute__((address_space(1))) unsigned int*)g,
      (__attribute__((address_space(3))) unsigned int*)l, 16, 0, 0);
}

// ---------------- prep: cast x -> bf16 AND transpose+cast both weights ----------------
// blocks [0,8192): x cast.  blocks [8192,12288): 32x32 transpose tiles.
__global__ __launch_bounds__(256) void prep_kernel(
    const float* __restrict__ x, unsigned short* __restrict__ x_bf,
    const float* __restrict__ Win, unsigned short* __restrict__ winT,
    const float* __restrict__ Wout, unsigned short* __restrict__ woutT) {
  __shared__ float tile[32][33];
  int bx = blockIdx.x;
  int tid = threadIdx.x;
  if (bx < 8192) {
    int i = bx * 256 + tid;
    float4 v = ((const float4*)x)[i];
    ushort4 o;
    o.x = f2bf(v.x); o.y = f2bf(v.y); o.z = f2bf(v.z); o.w = f2bf(v.w);
    ((ushort4*)x_bf)[i] = o;
  } else {
    int tb = bx - 8192;          // [0,4096): 128 n-tiles x 32 k-tiles
    int nt = tb & 127, kt = tb >> 7;
    const float* W;
    unsigned short* WT;
    int ncols, n0;
    if (nt < 96) { W = Win; WT = winT; ncols = 3072; n0 = nt * 32; }
    else { W = Wout; WT = woutT; ncols = 1024; n0 = (nt - 96) * 32; }
    int k0 = kt * 32;
    int tx = tid & 31, ty8 = tid >> 5;
#pragma unroll
    for (int r = 0; r < 4; r++) {
      int ty = ty8 + r * 8;
      tile[ty][tx] = W[(size_t)(k0 + ty) * ncols + n0 + tx];
    }
    __syncthreads();
#pragma unroll
    for (int r = 0; r < 4; r++) {
      int ty = ty8 + r * 8;
      WT[(size_t)(n0 + ty) * 1024 + k0 + tx] = f2bf(tile[tx][ty]);
    }
  }
}

// ---------------- GEMM (bf16 MFMA, K=1024 fixed) ----------------
// global_load_lds staging (width=16) with XOR chunk swizzle:
// chunk (row, q) lives at LDS As[row*32 + (q ^ ((row>>1)&3))*8]
// Epilogue: activation -> LDS tile (padded) -> coalesced 32B/lane stores.
// EPI==1: gemm1 -> bf16 silu(inp) / sigmoid(og) / om=1-lam (segment is
// block-uniform since n0 % 128 == 0 and segments are 1024 wide).
// EPI==0: gemm2 -> fp32 out + bias.
template <int EPI>
__global__ __launch_bounds__(256) void gemm_kernel(
    const unsigned short* __restrict__ A, const unsigned short* __restrict__ BT,
    const float* __restrict__ bias, const float* __restrict__ lb,
    float* __restrict__ outf,
    unsigned short* __restrict__ o_inp, unsigned short* __restrict__ o_og,
    unsigned short* __restrict__ o_om) {
  __shared__ alignas(16) char smem_raw[17408];  // staging 16KB | epi tile (<=16.9KB)
  unsigned short* As = (unsigned short*)smem_raw;
  unsigned short* Bs = As + 128 * 32;
  const int m0 = blockIdx.x * 128, n0 = blockIdx.y * 128;
  const int tid = threadIdx.x;
  const int lane = tid & 63, wave = tid >> 6;
  const int wm = (wave >> 1) * 64, wn = (wave & 1) * 64;
  const int mrow = lane & 15, q = lane >> 4;
  const int qsw = q ^ ((mrow >> 1) & 3);  // read-side swizzled chunk position
  floatx4 acc[4][4] = {};
  // staging: wave w covers rows [w*32, w*32+32); 2 instrs of 16 rows per matrix
  const int r0 = wave * 32;
  const int srow = r0 + (lane >> 2);
  const int qs = (lane & 3) ^ ((srow >> 1) & 3);  // global chunk this lane fetches
  const unsigned short* gA0 = A + (size_t)(m0 + srow) * 1024 + qs * 8;
  const unsigned short* gA1 = gA0 + (size_t)16 * 1024;
  const unsigned short* gB0 = BT + (size_t)(n0 + srow) * 1024 + qs * 8;
  const unsigned short* gB1 = gB0 + (size_t)16 * 1024;
  unsigned short* lA0 = &As[r0 * 32];
  unsigned short* lA1 = &As[(r0 + 16) * 32];
  unsigned short* lB0 = &Bs[r0 * 32];
  unsigned short* lB1 = &Bs[(r0 + 16) * 32];
  for (int kt = 0; kt < 1024; kt += 32) {
    __syncthreads();  // previous tile fully consumed
    async_copy16(gA0, lA0);
    async_copy16(gA1, lA1);
    async_copy16(gB0, lB0);
    async_copy16(gB1, lB1);
    gA0 += 32; gA1 += 32; gB0 += 32; gB1 += 32;
    __syncthreads();  // drains vmcnt -> staging complete
    bf16x8 af[4], bf[4];
#pragma unroll
    for (int i = 0; i < 4; i++) af[i] = *(const bf16x8*)&As[(wm + i * 16 + mrow) * 32 + qsw * 8];
#pragma unroll
    for (int j = 0; j < 4; j++) bf[j] = *(const bf16x8*)&Bs[(wn + j * 16 + mrow) * 32 + qsw * 8];
#pragma unroll
    for (int i = 0; i < 4; i++)
#pragma unroll
      for (int j = 0; j < 4; j++)
        acc[i][j] = __builtin_amdgcn_mfma_f32_16x16x32_bf16(af[i], bf[j], acc[i][j], 0, 0, 0);
  }
  // ---- epilogue ----
  const int er = tid >> 3;            // 0..31: local row for coalesced store
  const int ec = (tid & 7) * 16;      // 0..112: col chunk base
  const int rgbase = m0 + (er & 15) + (er >> 4) * 64;  // + i*16 later
  const int lr = (wm ? 16 : 0) + q * 4;                // local row base for C writes
  float bi[4];
  int cidx[4];
#pragma unroll
  for (int j = 0; j < 4; j++) {
    cidx[j] = n0 + wn + j * 16 + mrow;
    bi[j] = bias[cidx[j]];
  }
  if (EPI == 1) {
    unsigned short* Cs = (unsigned short*)smem_raw;  // 32 x 136 bf16
    const int seg = n0 >> 10;
    unsigned short* dst = (seg == 0) ? o_inp : (seg == 1) ? o_og : o_om;
    float Lv[4];
    if (seg == 2) {
#pragma unroll
      for (int j = 0; j < 4; j++) Lv[j] = lb[cidx[j] & 1023];
    }
#pragma unroll
    for (int i = 0; i < 4; i++) {
      __syncthreads();
#pragma unroll
      for (int j = 0; j < 4; j++) {
        const int lc = wn + j * 16 + mrow;
#pragma unroll
        for (int g = 0; g < 4; g++) {
          float v = acc[i][j][g] + bi[j];
          unsigned short ob;
          if (seg == 0) { float s = 1.f / (1.f + __expf(-v)); ob = f2bf(v * s); }
          else if (seg == 1) { float s = 1.f / (1.f + __expf(-v)); ob = f2bf(s); }
          else { float sm = 1.f / (1.f + __expf(v)); ob = f2bf((1.f - Lv[j]) * sm); }
          Cs[(lr + g) * 136 + lc] = ob;
        }
      }
      __syncthreads();
      uint4 v0 = *(uint4*)&Cs[er * 136 + ec];
      uint4 v1 = *(uint4*)&Cs[er * 136 + ec + 8];
      size_t ro = (size_t)(rgbase + i * 16) * 1024 + (n0 & 1023) + ec;
      *(uint4*)&dst[ro] = v0;
      *(uint4*)&dst[ro + 8] = v1;
    }
  } else {
    float* Cf = (float*)smem_raw;  // 32 x 132 fp32
#pragma unroll
    for (int i = 0; i < 4; i++) {
      __syncthreads();
#pragma unroll
      for (int j = 0; j < 4; j++) {
        const int lc = wn + j * 16 + mrow;
#pragma unroll
        for (int g = 0; g < 4; g++) Cf[(lr + g) * 132 + lc] = acc[i][j][g] + bi[j];
      }
      __syncthreads();
      size_t ro = (size_t)(rgbase + i * 16) * 1024 + n0 + ec;
#pragma unroll
      for (int k = 0; k < 4; k++) {
        float4 v = *(float4*)&Cf[er * 132 + ec + k * 4];
        *(float4*)&outf[ro + k * 4] = v;
      }
    }
  }
}

// ---------------- chunked bidirectional scan ----------------
// channel layout per (b,h): ch = dd*2+e;  a=lam[dd]=1-om[dd], u=om[dd]*inp[e]
// idx = (c*4 + b)*512 + h
__global__ void scan_passA(const unsigned short* __restrict__ om, const unsigned short* __restrict__ ip,
                           float* __restrict__ sumA, float* __restrict__ sumBf,
                           float* __restrict__ sumBr) {
  int idx = blockIdx.x * 256 + threadIdx.x;
  int h = idx & 511, cb = idx >> 9, b = cb & 3, c = cb >> 2;
  long base = ((long)c * CLEN * 4 + b) * 1024 + 2 * h;
  float p0 = 1.f, p1 = 1.f;
  float s00 = 0.f, s01 = 0.f, s10 = 0.f, s11 = 0.f;
  float r00 = 0.f, r01 = 0.f, r10 = 0.f, r11 = 0.f;
#pragma unroll
  for (int t = 0; t < CLEN; t++) {
    unsigned int l2 = *(const unsigned int*)(om + base);
    unsigned int i2 = *(const unsigned int*)(ip + base);
    base += 4096;
    float omx = bf2f_lo(l2), omy = bf2f_hi(l2);
    float ipx = bf2f_lo(i2), ipy = bf2f_hi(i2);
    float lx = 1.f - omx, ly = 1.f - omy;
    float u00 = omx * ipx, u01 = omx * ipy, u10 = omy * ipx, u11 = omy * ipy;
    r00 += p0 * u00; r01 += p0 * u01; r10 += p1 * u10; r11 += p1 * u11;
    s00 = lx * s00 + u00; s01 = lx * s01 + u01;
    s10 = ly * s10 + u10; s11 = ly * s11 + u11;
    p0 *= lx; p1 *= ly;
  }
  ((float2*)sumA)[idx] = make_float2(p0, p1);
  ((float4*)sumBf)[idx] = make_float4(s00, s01, s10, s11);
  ((float4*)sumBr)[idx] = make_float4(r00, r01, r10, r11);
}

// 256 blocks x 64 threads: one block per CU, short serial scan per thread.
__global__ void scan_passB(const float* __restrict__ sumA, const float* __restrict__ sumBf,
                           const float* __restrict__ sumBr, float* __restrict__ initF,
                           float* __restrict__ initR) {
  int tid = blockIdx.x * 64 + threadIdx.x;  // 16384
  int dir = tid >> 13;
  int rem = tid & 8191;   // (b*512+h)*4 + ch
  int ch = rem & 3;
  int bh = rem >> 2;
  int dd = ch >> 1;
  if (dir == 0) {
    float H = 0.f;
#pragma unroll 4
    for (int c = 0; c < NCH; c++) {
      int si = c * 2048 + bh;
      initF[(size_t)si * 4 + ch] = H;
      H = sumA[(size_t)si * 2 + dd] * H + sumBf[(size_t)si * 4 + ch];
    }
  } else {
    float G = 0.f;
#pragma unroll 4
    for (int c = NCH - 1; c >= 0; c--) {
      int si = c * 2048 + bh;
      initR[(size_t)si * 4 + ch] = G;
      G = sumA[(size_t)si * 2 + dd] * G + sumBr[(size_t)si * 4 + ch];
    }
  }
}

// ---- fused replay (fwd+rev) + layernorm -> bf16 y ----
// one block per (c,b): 512 threads, thread = h. Inputs loaded ONCE in the
// fwd loop and stashed in VGPRs (16 x 3 packed uints); rev loop replays
// from registers. LN via 8-row LDS transpose groups.
__global__ __launch_bounds__(512) void scanC_ln_kernel(
    const unsigned short* __restrict__ om, const unsigned short* __restrict__ ip,
    const unsigned short* __restrict__ og,
    const float* __restrict__ initF, const float* __restrict__ initR,
    const float* __restrict__ gamma, const float* __restrict__ beta,
    unsigned short* __restrict__ ybf) {
  __shared__ float tile[8][1024];
  __shared__ float ldsG[1024];
  __shared__ float ldsB[1024];
  const int h = threadIdx.x;  // 0..511
  const int cb = blockIdx.x;  // c*4 + b
  const int b = cb & 3, c = cb >> 2;
  const int idx = cb * 512 + h;
  // preload gamma/beta
  *(float2*)&ldsG[2 * h] = *(const float2*)(gamma + 2 * h);
  *(float2*)&ldsB[2 * h] = *(const float2*)(beta + 2 * h);
  float4 F = ((const float4*)initF)[idx];
  float4 R = ((const float4*)initR)[idx];
  float outx[CLEN], outy[CLEN];
  unsigned int lS[CLEN], iS[CLEN], oS[CLEN];
  const long base = ((long)c * CLEN * 4 + b) * 1024 + 2 * h;
  float h00 = F.x, h01 = F.y, h10 = F.z, h11 = F.w;
  long p = base;
#pragma unroll
  for (int t = 0; t < CLEN; t++) {
    unsigned int l2 = *(const unsigned int*)(om + p);
    unsigned int i2 = *(const unsigned int*)(ip + p);
    unsigned int o2 = *(const unsigned int*)(og + p);
    p += 4096;
    lS[t] = l2; iS[t] = i2; oS[t] = o2;
    float omx = bf2f_lo(l2), omy = bf2f_hi(l2);
    float ipx = bf2f_lo(i2), ipy = bf2f_hi(i2);
    float ox = bf2f_lo(o2), oy = bf2f_hi(o2);
    float lx = 1.f - omx, ly = 1.f - omy;
    h00 = lx * h00 + omx * ipx; h01 = lx * h01 + omx * ipy;
    h10 = ly * h10 + omy * ipx; h11 = ly * h11 + omy * ipy;
    outx[t] = h00 * ox + h10 * oy;
    outy[t] = h01 * ox + h11 * oy;
  }
  float g00 = R.x, g01 = R.y, g10 = R.z, g11 = R.w;
#pragma unroll
  for (int t = CLEN - 1; t >= 0; t--) {
    unsigned int l2 = lS[t], i2 = iS[t], o2 = oS[t];
    float omx = bf2f_lo(l2), omy = bf2f_hi(l2);
    float ipx = bf2f_lo(i2), ipy = bf2f_hi(i2);
    float ox = bf2f_lo(o2), oy = bf2f_hi(o2);
    float lx = 1.f - omx, ly = 1.f - omy;
    g00 = omx * ipx + lx * g00; g01 = omx * ipy + lx * g01;
    g10 = omy * ipx + ly * g10; g11 = omy * ipy + ly * g11;
    outx[t] += g00 * ox + g10 * oy;
    outy[t] += g01 * ox + g11 * oy;
  }
  // layernorm in groups of 8 t-rows via LDS transpose
  const int lane = h & 63, wv = h >> 6;
#pragma unroll
  for (int g = 0; g < CLEN / 8; g++) {
    __syncthreads();  // prior group reads done (and gamma/beta preload on g=0)
#pragma unroll
    for (int r = 0; r < 8; r++) {
      float2 v2 = make_float2(outx[g * 8 + r], outy[g * 8 + r]);
      *(float2*)&tile[r][2 * h] = v2;
    }
    __syncthreads();
    // wave wv reduces + normalizes row wv of this group
    {
      const int t = g * 8 + wv;
      float4 v[4];
#pragma unroll
      for (int k = 0; k < 4; k++) v[k] = *(const float4*)&tile[wv][lane * 16 + k * 4];
      float s = 0.f, s2 = 0.f;
#pragma unroll
      for (int k = 0; k < 4; k++) {
        s += v[k].x + v[k].y + v[k].z + v[k].w;
        s2 += v[k].x * v[k].x + v[k].y * v[k].y + v[k].z * v[k].z + v[k].w * v[k].w;
      }
#pragma unroll
      for (int off = 1; off < 64; off <<= 1) {
        s += __shfl_xor(s, off);
        s2 += __shfl_xor(s2, off);
      }
      float mean = s * (1.f / 1024.f);
      float var = s2 * (1.f / 1024.f) - mean * mean;
      float rstd = rsqrtf(var + 1e-5f);
      unsigned short o16[16];
#pragma unroll
      for (int k = 0; k < 4; k++) {
        float* vv = (float*)&v[k];
#pragma unroll
        for (int e = 0; e < 4; e++) {
          int ch = lane * 16 + k * 4 + e;
          o16[k * 4 + e] = f2bf((vv[e] - mean) * rstd * ldsG[ch] + ldsB[ch]);
        }
      }
      size_t rowo = ((size_t)(c * CLEN + t) * 4 + b) * 1024 + lane * 16;
      *(uint4*)(ybf + rowo) = *(uint4*)&o16[0];
      *(uint4*)(ybf + rowo + 8) = *(uint4*)&o16[8];
    }
  }
}

// ---------------- launch ----------------
extern "C" void kernel_launch(void* const* d_in, const int* in_sizes, int n_in,
                              void* d_out, int out_size, void* d_ws, size_t ws_size,
                              hipStream_t stream) {
  const float* x = (const float*)d_in[0];
  const float* lb = (const float*)d_in[1];
  const float* Win = (const float*)d_in[2];
  const float* bin = (const float*)d_in[3];
  const float* Wout = (const float*)d_in[4];
  const float* bout = (const float*)d_in[5];
  const float* gamma = (const float*)d_in[6];
  const float* beta = (const float*)d_in[7];
  float* out = (float*)d_out;

  char* ws = (char*)d_ws;
  size_t off = 0;
  auto alloc = [&](size_t bytes) {
    void* p = ws + off;
    off += (bytes + 255) & ~(size_t)255;
    return p;
  };
  unsigned short* x_bf = (unsigned short*)alloc(8192ull * 1024 * 2);
  unsigned short* winT = (unsigned short*)alloc(3072ull * 1024 * 2);
  unsigned short* woutT = (unsigned short*)alloc(1024ull * 1024 * 2);
  unsigned short* inp_b = (unsigned short*)alloc(8192ull * 1024 * 2);
  unsigned short* og_b = (unsigned short*)alloc(8192ull * 1024 * 2);
  unsigned short* om_b = (unsigned short*)alloc(8192ull * 1024 * 2);
  unsigned short* y_bf = (unsigned short*)alloc(8192ull * 1024 * 2);
  float* sumA = (float*)alloc((size_t)NCH * 4 * 512 * 2 * 4);
  float* sumBf = (float*)alloc((size_t)NCH * 4 * 512 * 4 * 4);
  float* sumBr = (float*)alloc((size_t)NCH * 4 * 512 * 4 * 4);
  float* initF = (float*)alloc((size_t)NCH * 4 * 512 * 4 * 4);
  float* initR = (float*)alloc((size_t)NCH * 4 * 512 * 4 * 4);

  prep_kernel<<<12288, 256, 0, stream>>>(x, x_bf, Win, winT, Wout, woutT);
  gemm_kernel<1><<<dim3(64, 24), 256, 0, stream>>>(x_bf, winT, bin, lb, nullptr, inp_b, og_b, om_b);
  scan_passA<<<(NCH * 4 * 512) / 256, 256, 0, stream>>>(om_b, inp_b, sumA, sumBf, sumBr);
  scan_passB<<<256, 64, 0, stream>>>(sumA, sumBf, sumBr, initF, initR);
  scanC_ln_kernel<<<NCH * 4, 512, 0, stream>>>(om_b, inp_b, og_b, initF, initR, gamma, beta, y_bf);
  gemm_kernel<0><<<dim3(64, 8), 256, 0, stream>>>(y_bf, woutT, bout, nullptr, out, nullptr, nullptr, nullptr);
}